// Round 8
// baseline (1050.300 us; speedup 1.0000x reference)
//
#include <hip/hip_runtime.h>
#include <hip/hip_bf16.h>
#include <math.h>

#define N_NODES 50000
#define NPAD    50048                  // N_NODES rounded up to 128 (gemm tiles, no guards)
#define N_EDGES 800000
#define EPRIME  (N_EDGES + N_NODES)   // edges + self loops
#define HEADS 8
#define CH 64
#define FDIM 512                       // HEADS*CH

typedef unsigned short ushort_t;
typedef __attribute__((ext_vector_type(8))) short bf16x8_t;  // 8 bf16 = 4 VGPRs
typedef __attribute__((ext_vector_type(4))) float f32x4_t;
typedef __attribute__((ext_vector_type(2))) float f32x2_t;   // packed fp32 (v_pk_*)

__device__ __forceinline__ float bf2f(unsigned short u) {
  union { unsigned int i; float f; } v; v.i = ((unsigned int)u) << 16; return v.f;
}
__device__ __forceinline__ unsigned short f2bf(float f) {
  union { float f; unsigned int i; } v; v.f = f;
  unsigned int x = v.i;
  return (unsigned short)((x + 0x7fffu + ((x >> 16) & 1u)) >> 16);  // RNE
}
__device__ __forceinline__ float ldf(const void* p, size_t idx, int isf32) {
  return isf32 ? ((const float*)p)[idx] : bf2f(((const ushort_t*)p)[idx]);
}
__device__ __forceinline__ void stf(void* p, size_t idx, float v, int isf32) {
  if (isf32) ((float*)p)[idx] = v;
  else       ((ushort_t*)p)[idx] = f2bf(v);
}
__device__ __forceinline__ float leakyf(float v) { return v >= 0.f ? v : 0.2f * v; }
__device__ __forceinline__ float eluf(float v)   { return v > 0.f ? v : expm1f(v); }

__device__ __forceinline__ f32x2_t sp2(float s) { return (f32x2_t){s, s}; }
// unpack a u32 holding two bf16 (lo = even channel, hi = odd channel) to f32x2
__device__ __forceinline__ f32x2_t bfpair(unsigned int u) {
  union { unsigned int i; float f; } lo, hi;
  lo.i = u << 16; hi.i = u & 0xffff0000u;
  return (f32x2_t){lo.f, hi.f};
}

// wave64 sum via DPP butterfly; full sum valid in lane 63. Pure VALU.
__device__ __forceinline__ float dpp_sum64(float x) {
  x += __int_as_float(__builtin_amdgcn_update_dpp(0, __float_as_int(x), 0xB1, 0xf, 0xf, false)); // quad_perm [1,0,3,2]
  x += __int_as_float(__builtin_amdgcn_update_dpp(0, __float_as_int(x), 0x4E, 0xf, 0xf, false)); // quad_perm [2,3,0,1]
  x += __int_as_float(__builtin_amdgcn_update_dpp(0, __float_as_int(x), 0x141, 0xf, 0xf, false)); // row_half_mirror
  x += __int_as_float(__builtin_amdgcn_update_dpp(0, __float_as_int(x), 0x140, 0xf, 0xf, false)); // row_mirror
  x += __int_as_float(__builtin_amdgcn_update_dpp(0, __float_as_int(x), 0x142, 0xa, 0xf, false)); // row_bcast:15 rows 1,3
  x += __int_as_float(__builtin_amdgcn_update_dpp(0, __float_as_int(x), 0x143, 0xc, 0xf, false)); // row_bcast:31 rows 2,3
  return x;
}

// async global->LDS, 16B per lane; LDS dest = wave-uniform base + lane*16
typedef const __attribute__((address_space(1))) unsigned int* gas1_t;
typedef __attribute__((address_space(3))) unsigned int* las3_t;
__device__ __forceinline__ void gll16(const ushort_t* g, ushort_t* l) {
  __builtin_amdgcn_global_load_lds((gas1_t)g, (las3_t)l, 16, 0, 0);
}

// ---------------- dtype detector (wave-parallel) ----------------
__global__ void detect_dtype(const void* Wn, int* flag) {
  const ushort_t* u = (const ushort_t*)Wn;
  int lane = threadIdx.x;
  int cnt = 0;
  for (int i = lane; i < 384; i += 64) {
    float v = fabsf(bf2f(u[i]));
    if (v != 0.f && (v > 16.f || v < 6.1e-5f)) cnt++;
  }
  #pragma unroll
  for (int off = 32; off > 0; off >>= 1) cnt += __shfl_down(cnt, off);
  if (lane == 0) *flag = (cnt >= 20) ? 1 : 0;
}

// ---------------- weight transpose-convert, LDS-tiled (coalesced both sides) --
// dst[n*K+k] = src[(boff+k)*N + n]; requires K,N multiples of 32.
__global__ __launch_bounds__(256) void convert_wt_t(const void* __restrict__ src,
                                                    ushort_t* __restrict__ dst,
                                                    int K, int N, int boff,
                                                    const int* __restrict__ dflag) {
  int isf32 = *dflag;
  __shared__ float tile[32][33];
  int n0 = blockIdx.x * 32, k0 = blockIdx.y * 32;
  int tx = threadIdx.x & 31, ty = threadIdx.x >> 5;   // 32 x 8
  #pragma unroll
  for (int r = 0; r < 4; ++r)
    tile[ty + 8 * r][tx] = ldf(src, (size_t)(boff + k0 + ty + 8 * r) * N + n0 + tx, isf32);
  __syncthreads();
  #pragma unroll
  for (int r = 0; r < 4; ++r)
    dst[(size_t)(n0 + ty + 8 * r) * K + k0 + tx] = f2bf(tile[tx][ty + 8 * r]);
}

// pack 6 attention vectors (3 layers x {a_src, a_dst}, 512 elems each) to bf16
__global__ void convert_att(const void* s1, const void* d1, const void* s2, const void* d2,
                            const void* s3, const void* d3, ushort_t* __restrict__ dst,
                            const int* __restrict__ dflag) {
  int isf32 = *dflag;
  int tid = blockIdx.x * blockDim.x + threadIdx.x;
  if (tid >= 6 * 512) return;
  int which = tid >> 9, idx = tid & 511;
  const void* p = which == 0 ? s1 : which == 1 ? d1 : which == 2 ? s2
                : which == 3 ? d2 : which == 4 ? s3 : d3;
  dst[tid] = f2bf(ldf(p, idx, isf32));
}

// ---------------- layer-1 attention in h-space ----------------
// wt_att[c*16 + head*2 + sd] = sum_ch W1[c, head*64+ch] * a_{src|dst}[head][ch]
__global__ void att_w1(const void* __restrict__ W1, const void* __restrict__ as1,
                       const void* __restrict__ ad1, float* __restrict__ wt_att,
                       const int* __restrict__ dflag) {
  int isf32 = *dflag;
  int t = blockIdx.x * blockDim.x + threadIdx.x;   // 0..1023
  if (t >= 64 * 16) return;
  int c = t >> 4, q = t & 15, head = q >> 1, sd = q & 1;
  const void* a = sd ? ad1 : as1;
  float s = 0.f;
  for (int ch = 0; ch < 64; ++ch)
    s += ldf(W1, (size_t)c * 512 + head * 64 + ch, isf32) * ldf(a, head * 64 + ch, isf32);
  wt_att[t] = s;
}

// per-node layer-1 coefs: asrc[n,h] = sum_c h[n,c]*wt[c*16+h*2]; adst at +1.
// block = 16 nodes x 16 coefs; h rows + wt staged in LDS.
__global__ __launch_bounds__(256) void coef1(const ushort_t* __restrict__ h,
                                             const float* __restrict__ wt_att,
                                             float* __restrict__ asrc,
                                             float* __restrict__ adst) {
  __shared__ float sh[16][64];
  __shared__ float sw[64][16];
  int t = threadIdx.x;
  int nb = blockIdx.x * 16;
  #pragma unroll
  for (int r = 0; r < 4; ++r) {
    int idx = t + 256 * r;                    // 0..1023
    sh[idx >> 6][idx & 63] = bf2f(h[(size_t)nb * 64 + idx]);
    sw[idx >> 4][idx & 15] = wt_att[idx];
  }
  __syncthreads();
  int node = t >> 4, q = t & 15;
  float s = 0.f;
  #pragma unroll
  for (int c = 0; c < 64; ++c) s += sh[node][c] * sw[c][q];
  int n = nb + node, head = q >> 1;
  if (q & 1) adst[n * 8 + head] = s;
  else       asrc[n * 8 + head] = s;
}

// layer-1 aggregation in h-space: agg[n, head*64+ch] = bf16(sum_e a*h[src,ch] / l).
// 128B gathers from the L2-resident h table instead of 1KB g-rows (8x less).
__global__ __launch_bounds__(256) void aggregate_h(
    const int* __restrict__ rowptr, const int* __restrict__ csr_src,
    const float* __restrict__ asrc, const float* __restrict__ adst,
    const ushort_t* __restrict__ h, ushort_t* __restrict__ agg)
{
  __shared__ float red[4][8][64];
  __shared__ float lred[4][8];
  int n = blockIdx.x;
  int t = threadIdx.x;
  int wave = t >> 6, lane = t & 63;
  int start = rowptr[n], end = rowptr[n + 1];
  const float4* adp = (const float4*)(adst + n * 8);
  float4 ad0 = adp[0], ad1v = adp[1];
  float accv[8], lv[8];
  #pragma unroll
  for (int k2 = 0; k2 < 8; ++k2) { accv[k2] = 0.f; lv[k2] = 0.f; }

  for (int i = start + wave; i < end; i += 4) {
    int iu = __builtin_amdgcn_readfirstlane(i);
    int s = csr_src[iu];
    float hv = bf2f(h[(size_t)s * 64 + lane]);
    const float4* ap = (const float4*)(asrc + s * 8);
    float4 a0 = ap[0], a1 = ap[1];
    float al[8];
    al[0] = __expf(leakyf(a0.x + ad0.x));
    al[1] = __expf(leakyf(a0.y + ad0.y));
    al[2] = __expf(leakyf(a0.z + ad0.z));
    al[3] = __expf(leakyf(a0.w + ad0.w));
    al[4] = __expf(leakyf(a1.x + ad1v.x));
    al[5] = __expf(leakyf(a1.y + ad1v.y));
    al[6] = __expf(leakyf(a1.z + ad1v.z));
    al[7] = __expf(leakyf(a1.w + ad1v.w));
    #pragma unroll
    for (int k2 = 0; k2 < 8; ++k2) { accv[k2] += al[k2] * hv; lv[k2] += al[k2]; }
  }

  #pragma unroll
  for (int k2 = 0; k2 < 8; ++k2) red[wave][k2][lane] = accv[k2];
  if (lane == 0) {
    #pragma unroll
    for (int k2 = 0; k2 < 8; ++k2) lred[wave][k2] = lv[k2];
  }
  __syncthreads();
  int hh = t >> 5, c0 = (t & 31) * 2;
  float l = lred[0][hh] + lred[1][hh] + lred[2][hh] + lred[3][hh];
  float rl = 1.f / l;
  float v0 = (red[0][hh][c0]     + red[1][hh][c0]     + red[2][hh][c0]     + red[3][hh][c0])     * rl;
  float v1 = (red[0][hh][c0 + 1] + red[1][hh][c0 + 1] + red[2][hh][c0 + 1] + red[3][hh][c0 + 1]) * rl;
  unsigned int o = (unsigned int)f2bf(v0) | ((unsigned int)f2bf(v1) << 16);
  *(unsigned int*)(agg + (size_t)n * FDIM + hh * 64 + c0) = o;
}

// block-diagonal per-head gemm + fused layer-1 epilogue:
// C[row,col] = sum_{k<64} agg[row, head(col)*64+k] * W1[k,col];
// o[row,col] = bf16(elu(C + bc1[col]) + (x@Wr + br)[row,col]).
// Fragments loaded straight from global (no LDS, no barriers); K=64 = 2 MFMA steps.
__global__ __launch_bounds__(256) void gemm_bd(
    const ushort_t* __restrict__ agg, const ushort_t* __restrict__ BT,   // BT=[512][64]
    ushort_t* __restrict__ o,
    const void* __restrict__ x, const void* __restrict__ Wr,
    const void* __restrict__ br, const void* __restrict__ bc,
    const int* __restrict__ dflag)
{
  int isf32 = *dflag;
  int tid = threadIdx.x;
  int wave = tid >> 6, lane = tid & 63;
  int wr_ = wave >> 1, wc = wave & 1;
  int row0 = blockIdx.x * 128, col0 = blockIdx.y * 128;
  int fm = lane & 15, fq = lane >> 4;

  f32x4_t acc[4][4];
  #pragma unroll
  for (int i = 0; i < 4; ++i)
    #pragma unroll
    for (int j = 0; j < 4; ++j) acc[i][j] = (f32x4_t){0.f, 0.f, 0.f, 0.f};

  #pragma unroll
  for (int ks = 0; ks < 2; ++ks) {
    bf16x8_t af[4], bfr[4];
    #pragma unroll
    for (int i = 0; i < 4; ++i)
      af[i] = *(const bf16x8_t*)(agg + (size_t)(row0 + 64 * wr_ + 16 * i + fm) * FDIM
                                     + col0 + 64 * wc + ks * 32 + fq * 8);
    #pragma unroll
    for (int j = 0; j < 4; ++j)
      bfr[j] = *(const bf16x8_t*)(BT + (size_t)(col0 + 64 * wc + 16 * j + fm) * 64
                                     + ks * 32 + fq * 8);
    #pragma unroll
    for (int i = 0; i < 4; ++i)
      #pragma unroll
      for (int j = 0; j < 4; ++j)
        acc[i][j] = __builtin_amdgcn_mfma_f32_16x16x32_bf16(af[i], bfr[j], acc[i][j], 0, 0, 0);
  }

  float wra[4], wrb[4], wrc[4], bb[4], brr[4];
  #pragma unroll
  for (int j = 0; j < 4; ++j) {
    int col = col0 + 64 * wc + 16 * j + fm;
    wra[j] = ldf(Wr, col, isf32);
    wrb[j] = ldf(Wr, 512 + col, isf32);
    wrc[j] = ldf(Wr, 1024 + col, isf32);
    brr[j] = ldf(br, col, isf32);
    bb[j]  = ldf(bc, col, isf32);
  }
  // C/D layout: col = lane&15, row = (lane>>4)*4 + reg
  #pragma unroll
  for (int i = 0; i < 4; ++i) {
    int rowb = row0 + 64 * wr_ + 16 * i + fq * 4;
    #pragma unroll
    for (int r = 0; r < 4; ++r) {
      int row = rowb + r;
      if (row < N_NODES) {
        float x0 = ldf(x, row * 3 + 0, isf32);
        float x1 = ldf(x, row * 3 + 1, isf32);
        float x2 = ldf(x, row * 3 + 2, isf32);
        #pragma unroll
        for (int j = 0; j < 4; ++j) {
          float rres = x0 * wra[j] + x1 * wrb[j] + x2 * wrc[j] + brr[j];
          float v = eluf(acc[i][j][r] + bb[j]) + rres;
          o[(size_t)row * FDIM + col0 + 64 * wc + 16 * j + fm] = f2bf(v);
        }
      }
    }
  }
}

// ---------------- CSR build ----------------
__global__ void init_deg(int* deg, int* fill) {
  int n = blockIdx.x * blockDim.x + threadIdx.x;
  if (n < N_NODES) { deg[n] = 1; fill[n] = 0; }   // 1 = self loop
}

__global__ void count_edges(const int* __restrict__ ei, int* deg) {
  int e = blockIdx.x * blockDim.x + threadIdx.x;
  if (e < N_EDGES) atomicAdd(&deg[ei[N_EDGES + e]], 1);
}

// parallel exclusive scan of deg[0..N_NODES) -> rowptr; 1 block x 1024 threads.
__global__ __launch_bounds__(1024) void scan1024(const int* __restrict__ deg,
                                                 int* __restrict__ rowptr) {
  const int CHUNK = (N_NODES + 1023) / 1024;   // 49
  int t = threadIdx.x;
  int wave = t >> 6, lane = t & 63;
  int lo = t * CHUNK;
  int hi = lo + CHUNK; if (hi > N_NODES) hi = N_NODES;
  int s = 0;
  for (int i = lo; i < hi; ++i) s += deg[i];
  int inc = s;
  #pragma unroll
  for (int off = 1; off < 64; off <<= 1) {
    int u = __shfl_up(inc, off);
    if (lane >= off) inc += u;
  }
  __shared__ int wsum[16];
  if (lane == 63) wsum[wave] = inc;
  __syncthreads();
  int wbase = 0;
  for (int w = 0; w < wave; ++w) wbase += wsum[w];
  int run = wbase + inc - s;                   // exclusive prefix for this thread
  for (int i = lo; i < hi; ++i) { rowptr[i] = run; run += deg[i]; }
  if (t == 1023) rowptr[N_NODES] = run;
}

__global__ void fill_csr(const int* __restrict__ ei, const int* __restrict__ rowptr,
                         int* fill, int* __restrict__ csr_src) {
  int e = blockIdx.x * blockDim.x + threadIdx.x;
  if (e >= EPRIME) return;
  int s, d;
  if (e < N_EDGES) { s = ei[e]; d = ei[N_EDGES + e]; }
  else             { s = d = e - N_EDGES; }
  int pos = rowptr[d] + atomicAdd(&fill[d], 1);
  csr_src[pos] = s;
}

// ---------------- node encoder ----------------
__global__ void encode_h(const void* __restrict__ x, const void* __restrict__ Wn,
                         const void* __restrict__ bn, ushort_t* __restrict__ h,
                         const int* __restrict__ dflag) {
  int isf32 = *dflag;
  int tid = blockIdx.x * blockDim.x + threadIdx.x;
  if (tid >= N_NODES * 64) return;
  int n = tid >> 6, j = tid & 63;
  float x0 = ldf(x, n * 3 + 0, isf32), x1 = ldf(x, n * 3 + 1, isf32), x2 = ldf(x, n * 3 + 2, isf32);
  float v = x0 * ldf(Wn, j, isf32) + x1 * ldf(Wn, 64 + j, isf32)
          + x2 * ldf(Wn, 128 + j, isf32) + ldf(bn, j, isf32);
  h[tid] = f2bf(v);
}

// ---------------- MFMA GEMM + fused attn-coef epilogue ------------------------
__global__ __launch_bounds__(256) void gemm_bt(
    const ushort_t* __restrict__ A, const ushort_t* __restrict__ BT,
    ushort_t* __restrict__ C, int K, int ldc,
    const ushort_t* __restrict__ att, float* __restrict__ asrc, float* __restrict__ adst)
{
  __shared__ __align__(16) ushort_t As[128][32];
  __shared__ __align__(16) ushort_t Bs[128][32];
  int tid = threadIdx.x;
  int wave = tid >> 6, lane = tid & 63;
  int wr = wave >> 1, wc = wave & 1;
  int row0 = blockIdx.x * 128, col0 = blockIdx.y * 128;
  int fm = lane & 15, fq = lane >> 4;

  f32x4_t acc[4][4];
  #pragma unroll
  for (int i = 0; i < 4; ++i)
    #pragma unroll
    for (int j = 0; j < 4; ++j) acc[i][j] = (f32x4_t){0.f, 0.f, 0.f, 0.f};

  int srow = wave * 32 + (lane >> 2);
  int skel = (lane & 3) * 8;
  const ushort_t* aG0 = A  + (size_t)(row0 + srow) * K + skel;
  const ushort_t* aG1 = A  + (size_t)(row0 + srow + 16) * K + skel;
  const ushort_t* bG0 = BT + (size_t)(col0 + srow) * K + skel;
  const ushort_t* bG1 = BT + (size_t)(col0 + srow + 16) * K + skel;
  ushort_t* aL0 = &As[wave * 32][0];
  ushort_t* aL1 = &As[wave * 32 + 16][0];
  ushort_t* bL0 = &Bs[wave * 32][0];
  ushort_t* bL1 = &Bs[wave * 32 + 16][0];

  for (int k0 = 0; k0 < K; k0 += 32) {
    gll16(aG0 + k0, aL0);
    gll16(aG1 + k0, aL1);
    gll16(bG0 + k0, bL0);
    gll16(bG1 + k0, bL1);
    __syncthreads();
    bf16x8_t af[4], bfr[4];
    #pragma unroll
    for (int i = 0; i < 4; ++i) af[i]  = *(const bf16x8_t*)&As[64 * wr + 16 * i + fm][fq * 8];
    #pragma unroll
    for (int j = 0; j < 4; ++j) bfr[j] = *(const bf16x8_t*)&Bs[64 * wc + 16 * j + fm][fq * 8];
    #pragma unroll
    for (int i = 0; i < 4; ++i)
      #pragma unroll
      for (int j = 0; j < 4; ++j)
        acc[i][j] = __builtin_amdgcn_mfma_f32_16x16x32_bf16(af[i], bfr[j], acc[i][j], 0, 0, 0);
    __syncthreads();
  }

  int do_att = (att != nullptr);
  int head = 2 * blockIdx.y + wc;
  float sa[4], sd[4];
  if (do_att) {
    #pragma unroll
    for (int j = 0; j < 4; ++j) {
      int ch = 16 * j + fm;
      sa[j] = bf2f(att[head * CH + ch]);
      sd[j] = bf2f(att[512 + head * CH + ch]);
    }
  }

  // C/D layout: col = lane&15, row = (lane>>4)*4 + reg
  #pragma unroll
  for (int i = 0; i < 4; ++i) {
    int rowb = row0 + 64 * wr + 16 * i + fq * 4;
    #pragma unroll
    for (int r = 0; r < 4; ++r) {
      int row = rowb + r;
      float ss = 0.f, dd = 0.f;
      #pragma unroll
      for (int j = 0; j < 4; ++j) {
        ushort_t uv = f2bf(acc[i][j][r]);
        C[(size_t)row * ldc + col0 + 64 * wc + 16 * j + fm] = uv;
        if (do_att) {
          float cv = bf2f(uv);
          ss += cv * sa[j];
          dd += cv * sd[j];
        }
      }
      if (do_att) {
        #pragma unroll
        for (int off = 8; off > 0; off >>= 1) {
          ss += __shfl_down(ss, off);
          dd += __shfl_down(dd, off);
        }
        if (fm == 0 && row < N_NODES) {
          asrc[row * HEADS + head] = ss;
          adst[row * HEADS + head] = dd;
        }
      }
    }
  }
}

// ---------------- aggregation (layers 2/3): wave-per-edge-subset, packed FMAs --
__global__ __launch_bounds__(256) void aggregate2(
    const int* __restrict__ rowptr, const int* __restrict__ csr_src,
    const float* __restrict__ asrc, const float* __restrict__ adst,
    float* __restrict__ sumv,
    const ushort_t* __restrict__ g,
    const void* __restrict__ x, const void* __restrict__ Wr,
    const void* __restrict__ br, const void* __restrict__ bc,
    ushort_t* __restrict__ out, int mean_mode,
    const void* __restrict__ Wo, const void* __restrict__ bo,
    void* __restrict__ outh, const int* __restrict__ dflag)
{
  int isf32 = *dflag;
  __shared__ float red[4][512];
  __shared__ float lred[4][8];
  __shared__ float sx[3];
  int n = blockIdx.x;
  int t = threadIdx.x;
  int wave = t >> 6, lane = t & 63;
  if (t < 3) sx[t] = ldf(x, n * 3 + t, isf32);

  int ch0 = lane * 8;        // 8 contiguous channels
  int hh  = lane >> 3;       // head owning these channels
  int start = rowptr[n], end = rowptr[n + 1];
  float ad = adst[n * HEADS + hh];

  f32x2_t acc2[4];
  #pragma unroll
  for (int k = 0; k < 4; ++k) acc2[k] = (f32x2_t){0.f, 0.f};
  float l = 0.f;

  int i = start + wave;
  for (; i + 4 < end; i += 8) {           // 2 edges in flight
    int iu0 = __builtin_amdgcn_readfirstlane(i);
    int iu1 = __builtin_amdgcn_readfirstlane(i + 4);
    int s0 = csr_src[iu0];
    int s1 = csr_src[iu1];
    float e0 = asrc[s0 * HEADS + hh] + ad;
    float e1 = asrc[s1 * HEADS + hh] + ad;
    uint4 gv0 = *(const uint4*)(g + (size_t)s0 * FDIM + ch0);
    uint4 gv1 = *(const uint4*)(g + (size_t)s1 * FDIM + ch0);
    float p0 = __expf(leakyf(e0));
    float p1 = __expf(leakyf(e1));
    l += p0 + p1;
    f32x2_t q0 = sp2(p0), q1 = sp2(p1);
    acc2[0] += q0 * bfpair(gv0.x); acc2[0] += q1 * bfpair(gv1.x);
    acc2[1] += q0 * bfpair(gv0.y); acc2[1] += q1 * bfpair(gv1.y);
    acc2[2] += q0 * bfpair(gv0.z); acc2[2] += q1 * bfpair(gv1.z);
    acc2[3] += q0 * bfpair(gv0.w); acc2[3] += q1 * bfpair(gv1.w);
  }
  if (i < end) {
    int iu0 = __builtin_amdgcn_readfirstlane(i);
    int s0 = csr_src[iu0];
    float e0 = asrc[s0 * HEADS + hh] + ad;
    uint4 gv0 = *(const uint4*)(g + (size_t)s0 * FDIM + ch0);
    float p0 = __expf(leakyf(e0));
    l += p0;
    f32x2_t q0 = sp2(p0);
    acc2[0] += q0 * bfpair(gv0.x);
    acc2[1] += q0 * bfpair(gv0.y);
    acc2[2] += q0 * bfpair(gv0.z);
    acc2[3] += q0 * bfpair(gv0.w);
  }

  #pragma unroll
  for (int k = 0; k < 4; ++k) {
    red[wave][ch0 + 2 * k]     = acc2[k][0];
    red[wave][ch0 + 2 * k + 1] = acc2[k][1];
  }
  if ((lane & 7) == 0) lred[wave][hh] = l;
  __syncthreads();

  // combine: thread t covers channels (2t, 2t+1), head t>>5 (old layout)
  int c0 = t * 2;
  int h  = t >> 5;
  float a0 = red[0][c0]     + red[1][c0]     + red[2][c0]     + red[3][c0];
  float a1 = red[0][c0 + 1] + red[1][c0 + 1] + red[2][c0 + 1] + red[3][c0 + 1];
  float lt = lred[0][h] + lred[1][h] + lred[2][h] + lred[3][h];
  a0 /= lt;
  a1 /= lt;
  if ((t & 31) == 0) sumv[n * HEADS + h] = 1.f / lt;   // reciprocal

  if (!mean_mode) {
    float r0 = sx[0] * ldf(Wr, c0, isf32)         + sx[1] * ldf(Wr, 512 + c0, isf32)
             + sx[2] * ldf(Wr, 1024 + c0, isf32)  + ldf(br, c0, isf32);
    float r1 = sx[0] * ldf(Wr, c0 + 1, isf32)     + sx[1] * ldf(Wr, 512 + c0 + 1, isf32)
             + sx[2] * ldf(Wr, 1024 + c0 + 1, isf32) + ldf(br, c0 + 1, isf32);
    unsigned int o0 = f2bf(eluf(a0 + ldf(bc, c0, isf32)) + r0);
    unsigned int o1 = f2bf(eluf(a1 + ldf(bc, c0 + 1, isf32)) + r1);
    *(unsigned int*)(out + (size_t)n * FDIM + c0) = o0 | (o1 << 16);
  } else {
    __syncthreads();                      // red[] reads above must complete
    red[0][c0] = a0; red[0][c0 + 1] = a1;
    __syncthreads();
    if (t < 64) {                               // wave 0, uniform branch
      float tot = 0.f;
      #pragma unroll
      for (int hh2 = 0; hh2 < 8; ++hh2) tot += red[0][t + 64 * hh2];
      ushort_t uv = f2bf(eluf(tot * 0.125f + ldf(bc, t, isf32)));
      out[(size_t)n * CH + t] = uv;
      // fused node head on the bf16-rounded ne value (matches old node_head)
      float nv = bf2f(uv);
      float p0 = nv * ldf(Wo, t * 2 + 0, isf32);
      float p1 = nv * ldf(Wo, t * 2 + 1, isf32);
      float vv = (t & 1) ? p1 : p0;
      float ww = (t & 1) ? p0 : p1;
      vv += __shfl_xor(ww, 1);
      #pragma unroll
      for (int off = 2; off < 64; off <<= 1) vv += __shfl_xor(vv, off);
      if (t < 2) stf(outh, (size_t)n * 2 + t, vv + ldf(bo, t, isf32), isf32);
    }
  }
}

// ---------------- edge head v8: packed math + 2-stage load pipeline -----------
#define EPW 32
__global__ __launch_bounds__(256) void edge_head8(
    const int* __restrict__ ei, const float* __restrict__ asrc, const float* __restrict__ adst,
    const float* __restrict__ rsumv,
    const ushort_t* __restrict__ pq, const void* __restrict__ Wm1,
    const void* __restrict__ bm1, const void* __restrict__ Wm2,
    const void* __restrict__ bm2, void* __restrict__ out,
    const int* __restrict__ dflag)
{
  int isf32 = *dflag;
  int lane = threadIdx.x & 63;
  int c0 = lane * 4;
  int h = lane & 7;
  f32x2_t w1r[8][2], w2a[2], w2b[2], b1r[2];
  #pragma unroll
  for (int hh = 0; hh < 8; ++hh)
    #pragma unroll
    for (int jp = 0; jp < 2; ++jp)
      w1r[hh][jp] = (f32x2_t){ ldf(Wm1, (64 + hh) * 256 + c0 + 2 * jp, isf32),
                               ldf(Wm1, (64 + hh) * 256 + c0 + 2 * jp + 1, isf32) };
  #pragma unroll
  for (int jp = 0; jp < 2; ++jp) {
    w2a[jp] = (f32x2_t){ ldf(Wm2, (c0 + 2 * jp) * 2 + 0, isf32),
                         ldf(Wm2, (c0 + 2 * jp + 1) * 2 + 0, isf32) };
    w2b[jp] = (f32x2_t){ ldf(Wm2, (c0 + 2 * jp) * 2 + 1, isf32),
                         ldf(Wm2, (c0 + 2 * jp + 1) * 2 + 1, isf32) };
    b1r[jp] = (f32x2_t){ ldf(bm1, c0 + 2 * jp, isf32),
                         ldf(bm1, c0 + 2 * jp + 1, isf32) };
  }
  float bo0 = ldf(bm2, 0, isf32), bo1 = ldf(bm2, 1, isf32);
  const f32x2_t zero2 = (f32x2_t){0.f, 0.f};

  int wid = blockIdx.x * 4 + (threadIdx.x >> 6);
  int e0 = wid * EPW;                       // EPW*4=128 divides N_EDGES exactly

  float vA, vB, rsA, rsB;
  uint2 pvA, qvA, pvB, qvB;
  {
    int eu = __builtin_amdgcn_readfirstlane(e0);
    int sA = ei[eu],     dA = ei[N_EDGES + eu];
    int sB = ei[eu + 1], dB = ei[N_EDGES + eu + 1];
    vA = asrc[sA * HEADS + h] + adst[dA * HEADS + h];
    vB = asrc[sB * HEADS + h] + adst[dB * HEADS + h];
    rsA = rsumv[dA * HEADS + h]; rsB = rsumv[dB * HEADS + h];
    pvA = *(const uint2*)(pq + (size_t)sA * FDIM + c0);
    qvA = *(const uint2*)(pq + (size_t)dA * FDIM + 256 + c0);
    pvB = *(const uint2*)(pq + (size_t)sB * FDIM + c0);
    qvB = *(const uint2*)(pq + (size_t)dB * FDIM + 256 + c0);
  }

  #pragma unroll
  for (int it = 0; it < EPW / 2; ++it) {
    int e = e0 + 2 * it;
    float cvA = vA, cvB = vB, crsA = rsA, crsB = rsB;
    uint2 cpvA = pvA, cqvA = qvA, cpvB = pvB, cqvB = qvB;
    if (it + 1 < EPW / 2) {
      int eu = __builtin_amdgcn_readfirstlane(e + 2);
      int sA = ei[eu],     dA = ei[N_EDGES + eu];
      int sB = ei[eu + 1], dB = ei[N_EDGES + eu + 1];
      vA = asrc[sA * HEADS + h] + adst[dA * HEADS + h];
      vB = asrc[sB * HEADS + h] + adst[dB * HEADS + h];
      rsA = rsumv[dA * HEADS + h]; rsB = rsumv[dB * HEADS + h];
      pvA = *(const uint2*)(pq + (size_t)sA * FDIM + c0);
      qvA = *(const uint2*)(pq + (size_t)dA * FDIM + 256 + c0);
      pvB = *(const uint2*)(pq + (size_t)sB * FDIM + c0);
      qvB = *(const uint2*)(pq + (size_t)dB * FDIM + 256 + c0);
    }

    float aA = __expf(leakyf(cvA)) * crsA;
    float aB = __expf(leakyf(cvB)) * crsB;
    float alA[8], alB[8];
    #pragma unroll
    for (int hh = 0; hh < 8; ++hh) {
      alA[hh] = __int_as_float(__builtin_amdgcn_readlane(__float_as_int(aA), hh));
      alB[hh] = __int_as_float(__builtin_amdgcn_readlane(__float_as_int(aB), hh));
    }

    f32x2_t pA2[2] = { bfpair(cpvA.x), bfpair(cpvA.y) };
    f32x2_t qA2[2] = { bfpair(cqvA.x), bfpair(cqvA.y) };
    f32x2_t pB2[2] = { bfpair(cpvB.x), bfpair(cpvB.y) };
    f32x2_t qB2[2] = { bfpair(cqvB.x), bfpair(cqvB.y) };
    f32x2_t aA0 = zero2, aA1 = zero2, aB0 = zero2, aB1 = zero2;
    #pragma unroll
    for (int jp = 0; jp < 2; ++jp) {
      f32x2_t hvA = pA2[jp] + qA2[jp] + b1r[jp];
      f32x2_t hvB = pB2[jp] + qB2[jp] + b1r[jp];
      #pragma unroll
      for (int hh = 0; hh < 8; ++hh) {
        hvA += sp2(alA[hh]) * w1r[hh][jp];
        hvB += sp2(alB[hh]) * w1r[hh][jp];
      }
      hvA = __builtin_elementwise_max(hvA, zero2);
      hvB = __builtin_elementwise_max(hvB, zero2);
      aA0 += hvA * w2a[jp]; aA1 += hvA * w2b[jp];
      aB0 += hvB * w2a[jp]; aB1 += hvB * w2b[jp];
    }
    float accA0 = aA0[0] + aA0[1];
    float accA1 = aA1[0] + aA1[1];
    float accB0 = aB0[0] + aB0[1];
    float accB1 = aB1[0] + aB1[1];
    accA0 = dpp_sum64(accA0);
    accA1 = dpp_sum64(accA1);
    accB0 = dpp_sum64(accB0);
    accB1 = dpp_sum64(accB1);
    if (lane == 63) {
      stf(out, 100000 + (size_t)e * 2 + 0, accA0 + bo0, isf32);
      stf(out, 100000 + (size_t)e * 2 + 1, accA1 + bo1, isf32);
      stf(out, 100000 + (size_t)e * 2 + 2, accB0 + bo0, isf32);
      stf(out, 100000 + (size_t)e * 2 + 3, accB1 + bo1, isf32);
    }
  }
}

// ---------------- launch ----------------
extern "C" void kernel_launch(void* const* d_in, const int* in_sizes, int n_in,
                              void* d_out, int out_size, void* d_ws, size_t ws_size,
                              hipStream_t stream) {
  const void* x   = d_in[0];
  const int*  ei  = (const int*)d_in[1];
  const void* Wn  = d_in[4];
  const void* bn  = d_in[5];
  const void* Wr  = d_in[6];
  const void* br  = d_in[7];
  const void* W1  = d_in[8];
  const void* as1 = d_in[9];
  const void* ad1 = d_in[10];
  const void* bc1 = d_in[11];
  const void* W2  = d_in[12];
  const void* as2 = d_in[13];
  const void* ad2 = d_in[14];
  const void* bc2 = d_in[15];
  const void* W3  = d_in[16];
  const void* as3 = d_in[17];
  const void* ad3 = d_in[18];
  const void* bc3 = d_in[19];
  const void* Wo  = d_in[20];
  const void* bo  = d_in[21];
  const void* Wm1 = d_in[22];
  const void* bm1 = d_in[23];
  const void* Wm2 = d_in[24];
  const void* bm2 = d_in[25];

  char* ws = (char*)d_ws;
  size_t off = 0;
  auto take = [&](size_t bytes) -> char* {
    char* p = ws + off;
    off += (bytes + 255) & ~(size_t)255;
    return p;
  };
  ushort_t* h_bf   = (ushort_t*)take((size_t)NPAD * 64 * 2);       // enc out / node_embedding
  ushort_t* g_bf   = (ushort_t*)take((size_t)NPAD * FDIM * 2);     // agg / gemm out / P|Q
  ushort_t* o_bf   = (ushort_t*)take((size_t)NPAD * FDIM * 2);     // layer out
  float*    asrc   = (float*)take((size_t)N_NODES * HEADS * 4);
  float*    adst   = (float*)take((size_t)N_NODES * HEADS * 4);
  float*    sumv   = (float*)take((size_t)N_NODES * HEADS * 4);
  int*      rowptr = (int*)take((size_t)(N_NODES + 1) * 4);
  int*      csr_src= (int*)take((size_t)EPRIME * 4);
  int*      deg    = (int*)take((size_t)N_NODES * 4);
  int*      fillc  = (int*)take((size_t)N_NODES * 4);
  int*      dflag  = (int*)take(256);
  ushort_t* WT1    = (ushort_t*)take((size_t)512 * 64 * 2);        // W1^T  [512][64]
  ushort_t* WT2    = (ushort_t*)take((size_t)512 * 512 * 2);       // W2^T  [512][512]
  ushort_t* WT3    = (ushort_t*)take((size_t)512 * 512 * 2);       // W3^T  [512][512]
  ushort_t* WTPQ   = (ushort_t*)take((size_t)512 * 64 * 2);        // [P^T ; Q^T] combined
  ushort_t* attv   = (ushort_t*)take((size_t)6 * 512 * 2);         // packed a_src/a_dst x3
  float*    wt_att = (float*)take((size_t)64 * 16 * 4);            // W1@a_{src,dst} [64][16]

  dim3 b256(256);
  const int MB = NPAD / 128;  // 391

  detect_dtype<<<dim3(1), dim3(64), 0, stream>>>(Wn, dflag);

  // weight conversion (LDS-tiled transpose to [n][k], bf16; coalesced both sides)
  convert_wt_t<<<dim3(16, 2),  b256, 0, stream>>>(W1, WT1, 64, 512, 0, dflag);
  convert_wt_t<<<dim3(16, 16), b256, 0, stream>>>(W2, WT2, 512, 512, 0, dflag);
  convert_wt_t<<<dim3(16, 16), b256, 0, stream>>>(W3, WT3, 512, 512, 0, dflag);
  convert_wt_t<<<dim3(8, 2),   b256, 0, stream>>>(Wm1, WTPQ,            64, 256, 0,  dflag);
  convert_wt_t<<<dim3(8, 2),   b256, 0, stream>>>(Wm1, WTPQ + 256 * 64, 64, 256, 72, dflag);
  convert_att<<<dim3(12),  b256, 0, stream>>>(as1, ad1, as2, ad2, as3, ad3, attv, dflag);
  att_w1<<<dim3(4), b256, 0, stream>>>(W1, as1, ad1, wt_att, dflag);

  // CSR build
  init_deg<<<dim3((N_NODES + 255) / 256), b256, 0, stream>>>(deg, fillc);
  count_edges<<<dim3((N_EDGES + 255) / 256), b256, 0, stream>>>(ei, deg);
  scan1024<<<dim3(1), dim3(1024), 0, stream>>>(deg, rowptr);
  fill_csr<<<dim3((EPRIME + 255) / 256), b256, 0, stream>>>(ei, rowptr, fillc, csr_src);

  // node encoder
  encode_h<<<dim3((N_NODES * 64 + 255) / 256), b256, 0, stream>>>(x, Wn, bn, h_bf, dflag);

  // ---- GAT layer 1 in h-space: coefs from h, aggregate 64-dim, block-diag gemm
  coef1<<<dim3(N_NODES / 16), b256, 0, stream>>>(h_bf, wt_att, asrc, adst);
  aggregate_h<<<dim3(N_NODES), b256, 0, stream>>>(rowptr, csr_src, asrc, adst,
                                                  h_bf, g_bf);
  gemm_bd<<<dim3(MB, 4), b256, 0, stream>>>(g_bf, WT1, o_bf, x, Wr, br, bc1, dflag);

  // ---- GAT layer 2 ----
  gemm_bt<<<dim3(MB, 4), b256, 0, stream>>>(o_bf, WT2, g_bf, 512, 512,
                                            attv + 1024, asrc, adst);
  aggregate2<<<dim3(N_NODES), b256, 0, stream>>>(rowptr, csr_src, asrc, adst, sumv,
                                                 g_bf, x, Wr, br, bc2, o_bf, 0,
                                                 nullptr, nullptr, d_out, dflag);

  // ---- GAT layer 3 (mean over heads -> ne in h_bf; node head fused) ----
  gemm_bt<<<dim3(MB, 4), b256, 0, stream>>>(o_bf, WT3, g_bf, 512, 512,
                                            attv + 2048, asrc, adst);
  aggregate2<<<dim3(N_NODES), b256, 0, stream>>>(rowptr, csr_src, asrc, adst, sumv,
                                                 g_bf, x, Wr, br, bc3, h_bf, 1,
                                                 Wo, bo, d_out, dflag);

  // ---- edge head: P|Q in one gemm, then per-edge MLP (pipelined, packed) ----
  gemm_bt<<<dim3(MB, 4), b256, 0, stream>>>(h_bf, WTPQ, g_bf, 64, 512,
                                            nullptr, nullptr, nullptr);
  edge_head8<<<dim3(N_EDGES / (EPW * 4)), b256, 0, stream>>>(ei, asrc, adst, sumv, g_bf,
                                                             Wm1, bm1, Wm2, bm2,
                                                             d_out, dflag);
}

// Round 9
// 1016.163 us; speedup vs baseline: 1.0336x; 1.0336x over previous
//
#include <hip/hip_runtime.h>
#include <hip/hip_bf16.h>
#include <math.h>

#define N_NODES 50000
#define NPAD    50048                  // N_NODES rounded up to 128 (gemm tiles, no guards)
#define N_EDGES 800000
#define EPRIME  (N_EDGES + N_NODES)   // edges + self loops
#define HEADS 8
#define CH 64
#define FDIM 512                       // HEADS*CH

typedef unsigned short ushort_t;
typedef __attribute__((ext_vector_type(8))) short bf16x8_t;  // 8 bf16 = 4 VGPRs
typedef __attribute__((ext_vector_type(4))) float f32x4_t;
typedef __attribute__((ext_vector_type(2))) float f32x2_t;   // packed fp32 (v_pk_*)

__device__ __forceinline__ float bf2f(unsigned short u) {
  union { unsigned int i; float f; } v; v.i = ((unsigned int)u) << 16; return v.f;
}
__device__ __forceinline__ unsigned short f2bf(float f) {
  union { float f; unsigned int i; } v; v.f = f;
  unsigned int x = v.i;
  return (unsigned short)((x + 0x7fffu + ((x >> 16) & 1u)) >> 16);  // RNE
}
__device__ __forceinline__ float ldf(const void* p, size_t idx, int isf32) {
  return isf32 ? ((const float*)p)[idx] : bf2f(((const ushort_t*)p)[idx]);
}
__device__ __forceinline__ void stf(void* p, size_t idx, float v, int isf32) {
  if (isf32) ((float*)p)[idx] = v;
  else       ((ushort_t*)p)[idx] = f2bf(v);
}
__device__ __forceinline__ float leakyf(float v) { return v >= 0.f ? v : 0.2f * v; }
__device__ __forceinline__ float eluf(float v)   { return v > 0.f ? v : expm1f(v); }

__device__ __forceinline__ f32x2_t sp2(float s) { return (f32x2_t){s, s}; }
// unpack a u32 holding two bf16 (lo = even channel, hi = odd channel) to f32x2
__device__ __forceinline__ f32x2_t bfpair(unsigned int u) {
  union { unsigned int i; float f; } lo, hi;
  lo.i = u << 16; hi.i = u & 0xffff0000u;
  return (f32x2_t){lo.f, hi.f};
}

// wave64 sum via DPP butterfly; full sum valid in lane 63. Pure VALU.
__device__ __forceinline__ float dpp_sum64(float x) {
  x += __int_as_float(__builtin_amdgcn_update_dpp(0, __float_as_int(x), 0xB1, 0xf, 0xf, false)); // quad_perm [1,0,3,2]
  x += __int_as_float(__builtin_amdgcn_update_dpp(0, __float_as_int(x), 0x4E, 0xf, 0xf, false)); // quad_perm [2,3,0,1]
  x += __int_as_float(__builtin_amdgcn_update_dpp(0, __float_as_int(x), 0x141, 0xf, 0xf, false)); // row_half_mirror
  x += __int_as_float(__builtin_amdgcn_update_dpp(0, __float_as_int(x), 0x140, 0xf, 0xf, false)); // row_mirror
  x += __int_as_float(__builtin_amdgcn_update_dpp(0, __float_as_int(x), 0x142, 0xa, 0xf, false)); // row_bcast:15 rows 1,3
  x += __int_as_float(__builtin_amdgcn_update_dpp(0, __float_as_int(x), 0x143, 0xc, 0xf, false)); // row_bcast:31 rows 2,3
  return x;
}

// async global->LDS, 16B per lane; LDS dest = wave-uniform base + lane*16
typedef const __attribute__((address_space(1))) unsigned int* gas1_t;
typedef __attribute__((address_space(3))) unsigned int* las3_t;
__device__ __forceinline__ void gll16(const ushort_t* g, ushort_t* l) {
  __builtin_amdgcn_global_load_lds((gas1_t)g, (las3_t)l, 16, 0, 0);
}

// ---------------- dtype detector (wave-parallel) ----------------
__global__ void detect_dtype(const void* Wn, int* flag) {
  const ushort_t* u = (const ushort_t*)Wn;
  int lane = threadIdx.x;
  int cnt = 0;
  for (int i = lane; i < 384; i += 64) {
    float v = fabsf(bf2f(u[i]));
    if (v != 0.f && (v > 16.f || v < 6.1e-5f)) cnt++;
  }
  #pragma unroll
  for (int off = 32; off > 0; off >>= 1) cnt += __shfl_down(cnt, off);
  if (lane == 0) *flag = (cnt >= 20) ? 1 : 0;
}

// ---------------- weight transpose-convert, LDS-tiled (coalesced both sides) --
// dst[n*K+k] = src[(boff+k)*N + n]; requires K,N multiples of 32.
__global__ __launch_bounds__(256) void convert_wt_t(const void* __restrict__ src,
                                                    ushort_t* __restrict__ dst,
                                                    int K, int N, int boff,
                                                    const int* __restrict__ dflag) {
  int isf32 = *dflag;
  __shared__ float tile[32][33];
  int n0 = blockIdx.x * 32, k0 = blockIdx.y * 32;
  int tx = threadIdx.x & 31, ty = threadIdx.x >> 5;   // 32 x 8
  #pragma unroll
  for (int r = 0; r < 4; ++r)
    tile[ty + 8 * r][tx] = ldf(src, (size_t)(boff + k0 + ty + 8 * r) * N + n0 + tx, isf32);
  __syncthreads();
  #pragma unroll
  for (int r = 0; r < 4; ++r)
    dst[(size_t)(n0 + ty + 8 * r) * K + k0 + tx] = f2bf(tile[tx][ty + 8 * r]);
}

// pack 6 attention vectors (3 layers x {a_src, a_dst}, 512 elems each) to bf16
__global__ void convert_att(const void* s1, const void* d1, const void* s2, const void* d2,
                            const void* s3, const void* d3, ushort_t* __restrict__ dst,
                            const int* __restrict__ dflag) {
  int isf32 = *dflag;
  int tid = blockIdx.x * blockDim.x + threadIdx.x;
  if (tid >= 6 * 512) return;
  int which = tid >> 9, idx = tid & 511;
  const void* p = which == 0 ? s1 : which == 1 ? d1 : which == 2 ? s2
                : which == 3 ? d2 : which == 4 ? s3 : d3;
  dst[tid] = f2bf(ldf(p, idx, isf32));
}

// ---------------- CSR build ----------------
__global__ void init_deg(int* deg, int* fill) {
  int n = blockIdx.x * blockDim.x + threadIdx.x;
  if (n < N_NODES) { deg[n] = 1; fill[n] = 0; }   // 1 = self loop
}

__global__ void count_edges(const int* __restrict__ ei, int* deg) {
  int e = blockIdx.x * blockDim.x + threadIdx.x;
  if (e < N_EDGES) atomicAdd(&deg[ei[N_EDGES + e]], 1);
}

// parallel exclusive scan of deg[0..N_NODES) -> rowptr; 1 block x 1024 threads.
__global__ __launch_bounds__(1024) void scan1024(const int* __restrict__ deg,
                                                 int* __restrict__ rowptr) {
  const int CHUNK = (N_NODES + 1023) / 1024;   // 49
  int t = threadIdx.x;
  int wave = t >> 6, lane = t & 63;
  int lo = t * CHUNK;
  int hi = lo + CHUNK; if (hi > N_NODES) hi = N_NODES;
  int s = 0;
  for (int i = lo; i < hi; ++i) s += deg[i];
  int inc = s;
  #pragma unroll
  for (int off = 1; off < 64; off <<= 1) {
    int u = __shfl_up(inc, off);
    if (lane >= off) inc += u;
  }
  __shared__ int wsum[16];
  if (lane == 63) wsum[wave] = inc;
  __syncthreads();
  int wbase = 0;
  for (int w = 0; w < wave; ++w) wbase += wsum[w];
  int run = wbase + inc - s;                   // exclusive prefix for this thread
  for (int i = lo; i < hi; ++i) { rowptr[i] = run; run += deg[i]; }
  if (t == 1023) rowptr[N_NODES] = run;
}

__global__ void fill_csr(const int* __restrict__ ei, const int* __restrict__ rowptr,
                         int* fill, int* __restrict__ csr_src) {
  int e = blockIdx.x * blockDim.x + threadIdx.x;
  if (e >= EPRIME) return;
  int s, d;
  if (e < N_EDGES) { s = ei[e]; d = ei[N_EDGES + e]; }
  else             { s = d = e - N_EDGES; }
  int pos = rowptr[d] + atomicAdd(&fill[d], 1);
  csr_src[pos] = s;
}

// ---------------- node encoder ----------------
__global__ void encode_h(const void* __restrict__ x, const void* __restrict__ Wn,
                         const void* __restrict__ bn, ushort_t* __restrict__ h,
                         const int* __restrict__ dflag) {
  int isf32 = *dflag;
  int tid = blockIdx.x * blockDim.x + threadIdx.x;
  if (tid >= N_NODES * 64) return;
  int n = tid >> 6, j = tid & 63;
  float x0 = ldf(x, n * 3 + 0, isf32), x1 = ldf(x, n * 3 + 1, isf32), x2 = ldf(x, n * 3 + 2, isf32);
  float v = x0 * ldf(Wn, j, isf32) + x1 * ldf(Wn, 64 + j, isf32)
          + x2 * ldf(Wn, 128 + j, isf32) + ldf(bn, j, isf32);
  h[tid] = f2bf(v);
}

// ---------------- MFMA GEMM + fused attn-coef epilogue ------------------------
__global__ __launch_bounds__(256) void gemm_bt(
    const ushort_t* __restrict__ A, const ushort_t* __restrict__ BT,
    ushort_t* __restrict__ C, int K, int ldc,
    const ushort_t* __restrict__ att, float* __restrict__ asrc, float* __restrict__ adst)
{
  __shared__ __align__(16) ushort_t As[128][32];
  __shared__ __align__(16) ushort_t Bs[128][32];
  int tid = threadIdx.x;
  int wave = tid >> 6, lane = tid & 63;
  int wr = wave >> 1, wc = wave & 1;
  int row0 = blockIdx.x * 128, col0 = blockIdx.y * 128;
  int fm = lane & 15, fq = lane >> 4;

  f32x4_t acc[4][4];
  #pragma unroll
  for (int i = 0; i < 4; ++i)
    #pragma unroll
    for (int j = 0; j < 4; ++j) acc[i][j] = (f32x4_t){0.f, 0.f, 0.f, 0.f};

  int srow = wave * 32 + (lane >> 2);
  int skel = (lane & 3) * 8;
  const ushort_t* aG0 = A  + (size_t)(row0 + srow) * K + skel;
  const ushort_t* aG1 = A  + (size_t)(row0 + srow + 16) * K + skel;
  const ushort_t* bG0 = BT + (size_t)(col0 + srow) * K + skel;
  const ushort_t* bG1 = BT + (size_t)(col0 + srow + 16) * K + skel;
  ushort_t* aL0 = &As[wave * 32][0];
  ushort_t* aL1 = &As[wave * 32 + 16][0];
  ushort_t* bL0 = &Bs[wave * 32][0];
  ushort_t* bL1 = &Bs[wave * 32 + 16][0];

  for (int k0 = 0; k0 < K; k0 += 32) {
    gll16(aG0 + k0, aL0);
    gll16(aG1 + k0, aL1);
    gll16(bG0 + k0, bL0);
    gll16(bG1 + k0, bL1);
    __syncthreads();
    bf16x8_t af[4], bfr[4];
    #pragma unroll
    for (int i = 0; i < 4; ++i) af[i]  = *(const bf16x8_t*)&As[64 * wr + 16 * i + fm][fq * 8];
    #pragma unroll
    for (int j = 0; j < 4; ++j) bfr[j] = *(const bf16x8_t*)&Bs[64 * wc + 16 * j + fm][fq * 8];
    #pragma unroll
    for (int i = 0; i < 4; ++i)
      #pragma unroll
      for (int j = 0; j < 4; ++j)
        acc[i][j] = __builtin_amdgcn_mfma_f32_16x16x32_bf16(af[i], bfr[j], acc[i][j], 0, 0, 0);
    __syncthreads();
  }

  int do_att = (att != nullptr);
  int head = 2 * blockIdx.y + wc;
  float sa[4], sd[4];
  if (do_att) {
    #pragma unroll
    for (int j = 0; j < 4; ++j) {
      int ch = 16 * j + fm;
      sa[j] = bf2f(att[head * CH + ch]);
      sd[j] = bf2f(att[512 + head * CH + ch]);
    }
  }

  // C/D layout: col = lane&15, row = (lane>>4)*4 + reg
  #pragma unroll
  for (int i = 0; i < 4; ++i) {
    int rowb = row0 + 64 * wr + 16 * i + fq * 4;
    #pragma unroll
    for (int r = 0; r < 4; ++r) {
      int row = rowb + r;
      float ss = 0.f, dd = 0.f;
      #pragma unroll
      for (int j = 0; j < 4; ++j) {
        ushort_t uv = f2bf(acc[i][j][r]);
        C[(size_t)row * ldc + col0 + 64 * wc + 16 * j + fm] = uv;
        if (do_att) {
          float cv = bf2f(uv);
          ss += cv * sa[j];
          dd += cv * sd[j];
        }
      }
      if (do_att) {
        #pragma unroll
        for (int off = 8; off > 0; off >>= 1) {
          ss += __shfl_down(ss, off);
          dd += __shfl_down(dd, off);
        }
        if (fm == 0 && row < N_NODES) {
          asrc[row * HEADS + head] = ss;
          adst[row * HEADS + head] = dd;
        }
      }
    }
  }
}

// ---------------- aggregation: wave-per-edge-subset, packed-f32 FMAs ----------
__global__ __launch_bounds__(256) void aggregate2(
    const int* __restrict__ rowptr, const int* __restrict__ csr_src,
    const float* __restrict__ asrc, const float* __restrict__ adst,
    float* __restrict__ sumv,
    const ushort_t* __restrict__ g,
    const void* __restrict__ x, const void* __restrict__ Wr,
    const void* __restrict__ br, const void* __restrict__ bc,
    ushort_t* __restrict__ out, int mean_mode,
    const void* __restrict__ Wo, const void* __restrict__ bo,
    void* __restrict__ outh, const int* __restrict__ dflag)
{
  int isf32 = *dflag;
  __shared__ float red[4][512];
  __shared__ float lred[4][8];
  __shared__ float sx[3];
  int n = blockIdx.x;
  int t = threadIdx.x;
  int wave = t >> 6, lane = t & 63;
  if (t < 3) sx[t] = ldf(x, n * 3 + t, isf32);

  int ch0 = lane * 8;        // 8 contiguous channels
  int hh  = lane >> 3;       // head owning these channels
  int start = rowptr[n], end = rowptr[n + 1];
  float ad = adst[n * HEADS + hh];

  f32x2_t acc2[4];
  #pragma unroll
  for (int k = 0; k < 4; ++k) acc2[k] = (f32x2_t){0.f, 0.f};
  float l = 0.f;

  int i = start + wave;
  for (; i + 4 < end; i += 8) {           // 2 edges in flight
    int iu0 = __builtin_amdgcn_readfirstlane(i);
    int iu1 = __builtin_amdgcn_readfirstlane(i + 4);
    int s0 = csr_src[iu0];
    int s1 = csr_src[iu1];
    float e0 = asrc[s0 * HEADS + hh] + ad;
    float e1 = asrc[s1 * HEADS + hh] + ad;
    uint4 gv0 = *(const uint4*)(g + (size_t)s0 * FDIM + ch0);
    uint4 gv1 = *(const uint4*)(g + (size_t)s1 * FDIM + ch0);
    float p0 = __expf(leakyf(e0));
    float p1 = __expf(leakyf(e1));
    l += p0 + p1;
    f32x2_t q0 = sp2(p0), q1 = sp2(p1);
    acc2[0] += q0 * bfpair(gv0.x); acc2[0] += q1 * bfpair(gv1.x);
    acc2[1] += q0 * bfpair(gv0.y); acc2[1] += q1 * bfpair(gv1.y);
    acc2[2] += q0 * bfpair(gv0.z); acc2[2] += q1 * bfpair(gv1.z);
    acc2[3] += q0 * bfpair(gv0.w); acc2[3] += q1 * bfpair(gv1.w);
  }
  if (i < end) {
    int iu0 = __builtin_amdgcn_readfirstlane(i);
    int s0 = csr_src[iu0];
    float e0 = asrc[s0 * HEADS + hh] + ad;
    uint4 gv0 = *(const uint4*)(g + (size_t)s0 * FDIM + ch0);
    float p0 = __expf(leakyf(e0));
    l += p0;
    f32x2_t q0 = sp2(p0);
    acc2[0] += q0 * bfpair(gv0.x);
    acc2[1] += q0 * bfpair(gv0.y);
    acc2[2] += q0 * bfpair(gv0.z);
    acc2[3] += q0 * bfpair(gv0.w);
  }

  #pragma unroll
  for (int k = 0; k < 4; ++k) {
    red[wave][ch0 + 2 * k]     = acc2[k][0];
    red[wave][ch0 + 2 * k + 1] = acc2[k][1];
  }
  if ((lane & 7) == 0) lred[wave][hh] = l;
  __syncthreads();

  // combine: thread t covers channels (2t, 2t+1), head t>>5 (old layout)
  int c0 = t * 2;
  int h  = t >> 5;
  float a0 = red[0][c0]     + red[1][c0]     + red[2][c0]     + red[3][c0];
  float a1 = red[0][c0 + 1] + red[1][c0 + 1] + red[2][c0 + 1] + red[3][c0 + 1];
  float lt = lred[0][h] + lred[1][h] + lred[2][h] + lred[3][h];
  a0 /= lt;
  a1 /= lt;
  if ((t & 31) == 0) sumv[n * HEADS + h] = 1.f / lt;   // reciprocal

  if (!mean_mode) {
    float r0 = sx[0] * ldf(Wr, c0, isf32)         + sx[1] * ldf(Wr, 512 + c0, isf32)
             + sx[2] * ldf(Wr, 1024 + c0, isf32)  + ldf(br, c0, isf32);
    float r1 = sx[0] * ldf(Wr, c0 + 1, isf32)     + sx[1] * ldf(Wr, 512 + c0 + 1, isf32)
             + sx[2] * ldf(Wr, 1024 + c0 + 1, isf32) + ldf(br, c0 + 1, isf32);
    unsigned int o0 = f2bf(eluf(a0 + ldf(bc, c0, isf32)) + r0);
    unsigned int o1 = f2bf(eluf(a1 + ldf(bc, c0 + 1, isf32)) + r1);
    *(unsigned int*)(out + (size_t)n * FDIM + c0) = o0 | (o1 << 16);
  } else {
    __syncthreads();                      // red[] reads above must complete
    red[0][c0] = a0; red[0][c0 + 1] = a1;
    __syncthreads();
    if (t < 64) {                               // wave 0, uniform branch
      float tot = 0.f;
      #pragma unroll
      for (int hh2 = 0; hh2 < 8; ++hh2) tot += red[0][t + 64 * hh2];
      ushort_t uv = f2bf(eluf(tot * 0.125f + ldf(bc, t, isf32)));
      out[(size_t)n * CH + t] = uv;
      // fused node head on the bf16-rounded ne value (matches old node_head)
      float nv = bf2f(uv);
      float p0 = nv * ldf(Wo, t * 2 + 0, isf32);
      float p1 = nv * ldf(Wo, t * 2 + 1, isf32);
      float vv = (t & 1) ? p1 : p0;
      float ww = (t & 1) ? p0 : p1;
      vv += __shfl_xor(ww, 1);
      #pragma unroll
      for (int off = 2; off < 64; off <<= 1) vv += __shfl_xor(vv, off);
      if (t < 2) stf(outh, (size_t)n * 2 + t, vv + ldf(bo, t, isf32), isf32);
    }
  }
}

// ---------------- edge head v8: packed math + 2-stage load pipeline -----------
#define EPW 32
__global__ __launch_bounds__(256) void edge_head8(
    const int* __restrict__ ei, const float* __restrict__ asrc, const float* __restrict__ adst,
    const float* __restrict__ rsumv,
    const ushort_t* __restrict__ pq, const void* __restrict__ Wm1,
    const void* __restrict__ bm1, const void* __restrict__ Wm2,
    const void* __restrict__ bm2, void* __restrict__ out,
    const int* __restrict__ dflag)
{
  int isf32 = *dflag;
  int lane = threadIdx.x & 63;
  int c0 = lane * 4;
  int h = lane & 7;
  f32x2_t w1r[8][2], w2a[2], w2b[2], b1r[2];
  #pragma unroll
  for (int hh = 0; hh < 8; ++hh)
    #pragma unroll
    for (int jp = 0; jp < 2; ++jp)
      w1r[hh][jp] = (f32x2_t){ ldf(Wm1, (64 + hh) * 256 + c0 + 2 * jp, isf32),
                               ldf(Wm1, (64 + hh) * 256 + c0 + 2 * jp + 1, isf32) };
  #pragma unroll
  for (int jp = 0; jp < 2; ++jp) {
    w2a[jp] = (f32x2_t){ ldf(Wm2, (c0 + 2 * jp) * 2 + 0, isf32),
                         ldf(Wm2, (c0 + 2 * jp + 1) * 2 + 0, isf32) };
    w2b[jp] = (f32x2_t){ ldf(Wm2, (c0 + 2 * jp) * 2 + 1, isf32),
                         ldf(Wm2, (c0 + 2 * jp + 1) * 2 + 1, isf32) };
    b1r[jp] = (f32x2_t){ ldf(bm1, c0 + 2 * jp, isf32),
                         ldf(bm1, c0 + 2 * jp + 1, isf32) };
  }
  float bo0 = ldf(bm2, 0, isf32), bo1 = ldf(bm2, 1, isf32);
  const f32x2_t zero2 = (f32x2_t){0.f, 0.f};

  int wid = blockIdx.x * 4 + (threadIdx.x >> 6);
  int e0 = wid * EPW;                       // EPW*4=128 divides N_EDGES exactly

  float vA, vB, rsA, rsB;
  uint2 pvA, qvA, pvB, qvB;
  {
    int eu = __builtin_amdgcn_readfirstlane(e0);
    int sA = ei[eu],     dA = ei[N_EDGES + eu];
    int sB = ei[eu + 1], dB = ei[N_EDGES + eu + 1];
    vA = asrc[sA * HEADS + h] + adst[dA * HEADS + h];
    vB = asrc[sB * HEADS + h] + adst[dB * HEADS + h];
    rsA = rsumv[dA * HEADS + h]; rsB = rsumv[dB * HEADS + h];
    pvA = *(const uint2*)(pq + (size_t)sA * FDIM + c0);
    qvA = *(const uint2*)(pq + (size_t)dA * FDIM + 256 + c0);
    pvB = *(const uint2*)(pq + (size_t)sB * FDIM + c0);
    qvB = *(const uint2*)(pq + (size_t)dB * FDIM + 256 + c0);
  }

  #pragma unroll
  for (int it = 0; it < EPW / 2; ++it) {
    int e = e0 + 2 * it;
    float cvA = vA, cvB = vB, crsA = rsA, crsB = rsB;
    uint2 cpvA = pvA, cqvA = qvA, cpvB = pvB, cqvB = qvB;
    if (it + 1 < EPW / 2) {
      int eu = __builtin_amdgcn_readfirstlane(e + 2);
      int sA = ei[eu],     dA = ei[N_EDGES + eu];
      int sB = ei[eu + 1], dB = ei[N_EDGES + eu + 1];
      vA = asrc[sA * HEADS + h] + adst[dA * HEADS + h];
      vB = asrc[sB * HEADS + h] + adst[dB * HEADS + h];
      rsA = rsumv[dA * HEADS + h]; rsB = rsumv[dB * HEADS + h];
      pvA = *(const uint2*)(pq + (size_t)sA * FDIM + c0);
      qvA = *(const uint2*)(pq + (size_t)dA * FDIM + 256 + c0);
      pvB = *(const uint2*)(pq + (size_t)sB * FDIM + c0);
      qvB = *(const uint2*)(pq + (size_t)dB * FDIM + 256 + c0);
    }

    float aA = __expf(leakyf(cvA)) * crsA;
    float aB = __expf(leakyf(cvB)) * crsB;
    float alA[8], alB[8];
    #pragma unroll
    for (int hh = 0; hh < 8; ++hh) {
      alA[hh] = __int_as_float(__builtin_amdgcn_readlane(__float_as_int(aA), hh));
      alB[hh] = __int_as_float(__builtin_amdgcn_readlane(__float_as_int(aB), hh));
    }

    f32x2_t pA2[2] = { bfpair(cpvA.x), bfpair(cpvA.y) };
    f32x2_t qA2[2] = { bfpair(cqvA.x), bfpair(cqvA.y) };
    f32x2_t pB2[2] = { bfpair(cpvB.x), bfpair(cpvB.y) };
    f32x2_t qB2[2] = { bfpair(cqvB.x), bfpair(cqvB.y) };
    f32x2_t aA0 = zero2, aA1 = zero2, aB0 = zero2, aB1 = zero2;
    #pragma unroll
    for (int jp = 0; jp < 2; ++jp) {
      f32x2_t hvA = pA2[jp] + qA2[jp] + b1r[jp];
      f32x2_t hvB = pB2[jp] + qB2[jp] + b1r[jp];
      #pragma unroll
      for (int hh = 0; hh < 8; ++hh) {
        hvA += sp2(alA[hh]) * w1r[hh][jp];
        hvB += sp2(alB[hh]) * w1r[hh][jp];
      }
      hvA = __builtin_elementwise_max(hvA, zero2);
      hvB = __builtin_elementwise_max(hvB, zero2);
      aA0 += hvA * w2a[jp]; aA1 += hvA * w2b[jp];
      aB0 += hvB * w2a[jp]; aB1 += hvB * w2b[jp];
    }
    float accA0 = aA0[0] + aA0[1];
    float accA1 = aA1[0] + aA1[1];
    float accB0 = aB0[0] + aB0[1];
    float accB1 = aB1[0] + aB1[1];
    accA0 = dpp_sum64(accA0);
    accA1 = dpp_sum64(accA1);
    accB0 = dpp_sum64(accB0);
    accB1 = dpp_sum64(accB1);
    if (lane == 63) {
      stf(out, 100000 + (size_t)e * 2 + 0, accA0 + bo0, isf32);
      stf(out, 100000 + (size_t)e * 2 + 1, accA1 + bo1, isf32);
      stf(out, 100000 + (size_t)e * 2 + 2, accB0 + bo0, isf32);
      stf(out, 100000 + (size_t)e * 2 + 3, accB1 + bo1, isf32);
    }
  }
}

// ---------------- launch ----------------
extern "C" void kernel_launch(void* const* d_in, const int* in_sizes, int n_in,
                              void* d_out, int out_size, void* d_ws, size_t ws_size,
                              hipStream_t stream) {
  const void* x   = d_in[0];
  const int*  ei  = (const int*)d_in[1];
  const void* Wn  = d_in[4];
  const void* bn  = d_in[5];
  const void* Wr  = d_in[6];
  const void* br  = d_in[7];
  const void* W1  = d_in[8];
  const void* as1 = d_in[9];
  const void* ad1 = d_in[10];
  const void* bc1 = d_in[11];
  const void* W2  = d_in[12];
  const void* as2 = d_in[13];
  const void* ad2 = d_in[14];
  const void* bc2 = d_in[15];
  const void* W3  = d_in[16];
  const void* as3 = d_in[17];
  const void* ad3 = d_in[18];
  const void* bc3 = d_in[19];
  const void* Wo  = d_in[20];
  const void* bo  = d_in[21];
  const void* Wm1 = d_in[22];
  const void* bm1 = d_in[23];
  const void* Wm2 = d_in[24];
  const void* bm2 = d_in[25];

  char* ws = (char*)d_ws;
  size_t off = 0;
  auto take = [&](size_t bytes) -> char* {
    char* p = ws + off;
    off += (bytes + 255) & ~(size_t)255;
    return p;
  };
  ushort_t* h_bf   = (ushort_t*)take((size_t)NPAD * 64 * 2);       // enc out / node_embedding
  ushort_t* g_bf   = (ushort_t*)take((size_t)NPAD * FDIM * 2);     // gemm out / P|Q
  ushort_t* o_bf   = (ushort_t*)take((size_t)NPAD * FDIM * 2);     // layer out
  float*    asrc   = (float*)take((size_t)N_NODES * HEADS * 4);
  float*    adst   = (float*)take((size_t)N_NODES * HEADS * 4);
  float*    sumv   = (float*)take((size_t)N_NODES * HEADS * 4);
  int*      rowptr = (int*)take((size_t)(N_NODES + 1) * 4);
  int*      csr_src= (int*)take((size_t)EPRIME * 4);
  int*      deg    = (int*)take((size_t)N_NODES * 4);
  int*      fillc  = (int*)take((size_t)N_NODES * 4);
  int*      dflag  = (int*)take(256);
  ushort_t* WT1    = (ushort_t*)take((size_t)512 * 64 * 2);        // W1^T  [512][64]
  ushort_t* WT2    = (ushort_t*)take((size_t)512 * 512 * 2);       // W2^T  [512][512]
  ushort_t* WT3    = (ushort_t*)take((size_t)512 * 512 * 2);       // W3^T  [512][512]
  ushort_t* WTPQ   = (ushort_t*)take((size_t)512 * 64 * 2);        // [P^T ; Q^T] combined
  ushort_t* attv   = (ushort_t*)take((size_t)6 * 512 * 2);         // packed a_src/a_dst x3

  dim3 b256(256);
  const int MB = NPAD / 128;  // 391

  detect_dtype<<<dim3(1), dim3(64), 0, stream>>>(Wn, dflag);

  // weight conversion (LDS-tiled transpose to [n][k], bf16; coalesced both sides)
  convert_wt_t<<<dim3(16, 2),  b256, 0, stream>>>(W1, WT1, 64, 512, 0, dflag);
  convert_wt_t<<<dim3(16, 16), b256, 0, stream>>>(W2, WT2, 512, 512, 0, dflag);
  convert_wt_t<<<dim3(16, 16), b256, 0, stream>>>(W3, WT3, 512, 512, 0, dflag);
  convert_wt_t<<<dim3(8, 2),   b256, 0, stream>>>(Wm1, WTPQ,            64, 256, 0,  dflag);
  convert_wt_t<<<dim3(8, 2),   b256, 0, stream>>>(Wm1, WTPQ + 256 * 64, 64, 256, 72, dflag);
  convert_att<<<dim3(12),  b256, 0, stream>>>(as1, ad1, as2, ad2, as3, ad3, attv, dflag);

  // CSR build
  init_deg<<<dim3((N_NODES + 255) / 256), b256, 0, stream>>>(deg, fillc);
  count_edges<<<dim3((N_EDGES + 255) / 256), b256, 0, stream>>>(ei, deg);
  scan1024<<<dim3(1), dim3(1024), 0, stream>>>(deg, rowptr);
  fill_csr<<<dim3((EPRIME + 255) / 256), b256, 0, stream>>>(ei, rowptr, fillc, csr_src);

  // node encoder
  encode_h<<<dim3((N_NODES * 64 + 255) / 256), b256, 0, stream>>>(x, Wn, bn, h_bf, dflag);

  // ---- GAT layer 1 (in: h_bf [NPAD,64]); attn fused in gemm epilogue ----
  gemm_bt<<<dim3(MB, 4), b256, 0, stream>>>(h_bf, WT1, g_bf, 64, 512,
                                            attv, asrc, adst);
  aggregate2<<<dim3(N_NODES), b256, 0, stream>>>(rowptr, csr_src, asrc, adst, sumv,
                                                 g_bf, x, Wr, br, bc1, o_bf, 0,
                                                 nullptr, nullptr, d_out, dflag);

  // ---- GAT layer 2 ----
  gemm_bt<<<dim3(MB, 4), b256, 0, stream>>>(o_bf, WT2, g_bf, 512, 512,
                                            attv + 1024, asrc, adst);
  aggregate2<<<dim3(N_NODES), b256, 0, stream>>>(rowptr, csr_src, asrc, adst, sumv,
                                                 g_bf, x, Wr, br, bc2, o_bf, 0,
                                                 nullptr, nullptr, d_out, dflag);

  // ---- GAT layer 3 (mean over heads -> ne in h_bf; node head fused) ----
  gemm_bt<<<dim3(MB, 4), b256, 0, stream>>>(o_bf, WT3, g_bf, 512, 512,
                                            attv + 2048, asrc, adst);
  aggregate2<<<dim3(N_NODES), b256, 0, stream>>>(rowptr, csr_src, asrc, adst, sumv,
                                                 g_bf, x, Wr, br, bc3, h_bf, 1,
                                                 Wo, bo, d_out, dflag);

  // ---- edge head: P|Q in one gemm, then per-edge MLP (pipelined, packed) ----
  gemm_bt<<<dim3(MB, 4), b256, 0, stream>>>(h_bf, WTPQ, g_bf, 64, 512,
                                            nullptr, nullptr, nullptr);
  edge_head8<<<dim3(N_EDGES / (EPW * 4)), b256, 0, stream>>>(ei, asrc, adst, sumv, g_bf,
                                                             Wm1, bm1, Wm2, bm2,
                                                             d_out, dflag);
}